// Round 2
// baseline (5466.965 us; speedup 1.0000x reference)
//
#include <hip/hip_runtime.h>
#include <hip/hip_bf16.h>
#include <math.h>

#define BATCH 2
#define SEQL 8192
#define DD 256
#define HDIM 1024
#define NLAYER 6
#define WSZ 512
#define NVOCAB 32
#define NTOK (BATCH*SEQL)   // 16384

typedef unsigned short u16;

__device__ inline float bf2f(u16 v){
  unsigned int u = ((unsigned int)v) << 16;
  return __uint_as_float(u);
}
__device__ inline u16 f2bf(float f){
  unsigned int u = __float_as_uint(f);
  u += 0x7fff + ((u >> 16) & 1);   // RNE
  return (u16)(u >> 16);
}
__device__ inline float4 bf4_to_f4(ushort4 v){
  return make_float4(bf2f(v.x), bf2f(v.y), bf2f(v.z), bf2f(v.w));
}

// ---------------- one-time rope tables (fp64 internally) ----------------
__global__ void k_tables(float* __restrict__ ct, float* __restrict__ st){
  int idx = blockIdx.x * 256 + threadIdx.x;     // t*128 + i
  if (idx >= SEQL * 128) return;
  int t = idx >> 7, i = idx & 127;
  double freq = exp(-((double)(2 * i) / (double)DD) * log(10000.0));
  double fr = (double)t * freq;
  ct[idx] = (float)cos(fr);
  st[idx] = (float)sin(fr);
}

// ---------------- embedding gather (fp32 table) ----------------
__global__ void k_embed(const int* __restrict__ tokens, const float* __restrict__ emb,
                        float* __restrict__ x){
  int idx = blockIdx.x * 256 + threadIdx.x;     // bt*64 + dvec
  int bt = idx >> 6, dv = (idx & 63) << 2;
  int tok = tokens[bt];
  *(float4*)(x + bt * DD + dv) = *(const float4*)(emb + tok * DD + dv);
}

// ---------------- rope: x(fp32) -> qk (roped, bf16) ----------------
__global__ void k_rope(const float* __restrict__ x, const float* __restrict__ ct,
                       const float* __restrict__ st, u16* __restrict__ qk){
  int idx = blockIdx.x * 256 + threadIdx.x;     // bt*32 + ivec  (half-dim /4)
  int bt = idx >> 5, iv = (idx & 31) << 2;
  int t = bt & (SEQL - 1);
  const float* xr = x + bt * DD;
  float4 x1 = *(const float4*)(xr + iv);
  float4 x2 = *(const float4*)(xr + 128 + iv);
  float4 c = *(const float4*)(ct + t * 128 + iv);
  float4 s = *(const float4*)(st + t * 128 + iv);
  ushort4 q1, q2;
  q1.x = f2bf(x1.x * c.x - x2.x * s.x);  q2.x = f2bf(x2.x * c.x + x1.x * s.x);
  q1.y = f2bf(x1.y * c.y - x2.y * s.y);  q2.y = f2bf(x2.y * c.y + x1.y * s.y);
  q1.z = f2bf(x1.z * c.z - x2.z * s.z);  q2.z = f2bf(x2.z * c.z + x1.z * s.z);
  q1.w = f2bf(x1.w * c.w - x2.w * s.w);  q2.w = f2bf(x2.w * c.w + x1.w * s.w);
  *(ushort4*)(qk + bt * DD + iv)       = q1;
  *(ushort4*)(qk + bt * DD + 128 + iv) = q2;
}

// ---------------- sliding-window attention: one wave per query ----------------
// keys = max(0, t-512) .. t (the lucidrains mask). Scores are tiny (|q.k|/16 << 1)
// so plain exp without max-subtraction is fp32-safe. V = raw x (fp32).
__global__ void __launch_bounds__(256) k_attn(const u16* __restrict__ qk,
                                              const float* __restrict__ x,
                                              float* __restrict__ y){
  int bt = (blockIdx.x * 256 + threadIdx.x) >> 6;   // global query index
  int lane = threadIdx.x & 63;
  int t = bt & (SEQL - 1);
  int base = bt * DD + lane * 4;
  float4 qf = bf4_to_f4(*(const ushort4*)(qk + base));
  const float sc = 0.0625f;                          // 256^-0.5
  float q0 = qf.x * sc, q1 = qf.y * sc, q2 = qf.z * sc, q3 = qf.w * sc;
  int k0 = t - WSZ; if (k0 < 0) k0 = 0;
  int nk = t - k0 + 1;
  const u16*  kp = qk + (size_t)(bt - (t - k0)) * DD + lane * 4;
  const float* vp = x  + (size_t)(bt - (t - k0)) * DD + lane * 4;
  float a0 = 0, a1 = 0, a2 = 0, a3 = 0, l = 0;
  for (int k = 0; k < nk; ++k){
    float4 kf = bf4_to_f4(*(const ushort4*)kp);
    float s = q0 * kf.x + q1 * kf.y + q2 * kf.z + q3 * kf.w;
    #pragma unroll
    for (int o = 32; o; o >>= 1) s += __shfl_xor(s, o, 64);
    float p = __expf(s);
    float4 vf = *(const float4*)vp;
    l += p;
    a0 += p * vf.x; a1 += p * vf.y; a2 += p * vf.z; a3 += p * vf.w;
    kp += DD; vp += DD;
  }
  float inv = 1.0f / l;
  float4 xr = *(const float4*)(x + base);
  float4 o = make_float4(xr.x + a0 * inv, xr.y + a1 * inv,
                         xr.z + a2 * inv, xr.w + a3 * inv);
  *(float4*)(y + base) = o;
}

// ---------------- layernorm (wave per token), fp32 in, bf16 out ----------------
__global__ void __launch_bounds__(256) k_ln(const float* __restrict__ in,
                                            const float* __restrict__ g,
                                            const float* __restrict__ b,
                                            u16* __restrict__ out){
  int wid = (blockIdx.x * 256 + threadIdx.x) >> 6;
  int lane = threadIdx.x & 63;
  float4 v = *(const float4*)(in + wid * DD + lane * 4);
  float s = v.x + v.y + v.z + v.w;
  float ss = v.x * v.x + v.y * v.y + v.z * v.z + v.w * v.w;
  #pragma unroll
  for (int o = 32; o; o >>= 1){ s += __shfl_xor(s, o, 64); ss += __shfl_xor(ss, o, 64); }
  float m = s * (1.0f / DD);
  float var = ss * (1.0f / DD) - m * m;
  float rs = rsqrtf(var + 1e-5f);
  float4 gf = *(const float4*)(g + lane * 4);
  float4 bf = *(const float4*)(b + lane * 4);
  ushort4 o4;
  o4.x = f2bf((v.x - m) * rs * gf.x + bf.x);
  o4.y = f2bf((v.y - m) * rs * gf.y + bf.y);
  o4.z = f2bf((v.z - m) * rs * gf.z + bf.z);
  o4.w = f2bf((v.w - m) * rs * gf.w + bf.w);
  *(ushort4*)(out + wid * DD + lane * 4) = o4;
}

// ---------------- mm1 + bias + exact gelu: (16384x256)@(256x1024) -> h bf16 ----
// tile 32 tokens x 128 cols, 256 threads, 4x4 micro-tile
__global__ void __launch_bounds__(256) k_mm1(const u16* __restrict__ lnx,
                                             const float* __restrict__ w1,
                                             const float* __restrict__ b1,
                                             u16* __restrict__ h){
  __shared__ u16 xs[32][264];
  int tT = blockIdx.y * 32;
  int cB = blockIdx.x * 128;
  for (int i = threadIdx.x; i < 32 * 64; i += 256){
    int r = i >> 6, c = (i & 63) << 2;
    *(ushort4*)&xs[r][c] = *(const ushort4*)(lnx + (tT + r) * DD + c);
  }
  __syncthreads();
  int cg = (threadIdx.x & 31) << 2;
  int rg = (threadIdx.x >> 5) << 2;
  float acc[4][4] = {};
  const float* wp = w1 + cB + cg;
  #pragma unroll 2
  for (int d = 0; d < DD; ++d){
    float4 wf = *(const float4*)(wp + d * HDIM);
    #pragma unroll
    for (int i = 0; i < 4; ++i){
      float xvv = bf2f(xs[rg + i][d]);
      acc[i][0] += xvv * wf.x; acc[i][1] += xvv * wf.y;
      acc[i][2] += xvv * wf.z; acc[i][3] += xvv * wf.w;
    }
  }
  float4 bf = *(const float4*)(b1 + cB + cg);
  float bias[4] = {bf.x, bf.y, bf.z, bf.w};
  for (int i = 0; i < 4; ++i){
    ushort4 o; u16* po = (u16*)&o;
    #pragma unroll
    for (int j = 0; j < 4; ++j){
      float v = acc[i][j] + bias[j];
      v = 0.5f * v * (1.0f + erff(v * 0.70710678f));
      po[j] = f2bf(v);
    }
    *(ushort4*)(h + (size_t)(tT + rg + i) * HDIM + cB + cg) = o;
  }
}

// ---------------- mm2 + bias + residual: (16384x1024)@(1024x256) + y -> x fp32 --
// tile 16 tokens x 256 cols, 256 threads, 4x4 micro-tile
__global__ void __launch_bounds__(256) k_mm2(const u16* __restrict__ h,
                                             const float* __restrict__ w2,
                                             const float* __restrict__ b2,
                                             const float* __restrict__ y,
                                             float* __restrict__ x){
  __shared__ u16 hs[16][1032];
  int tT = blockIdx.x * 16;
  for (int i = threadIdx.x; i < 16 * 256; i += 256){
    int r = i >> 8, c = (i & 255) << 2;
    *(ushort4*)&hs[r][c] = *(const ushort4*)(h + (size_t)(tT + r) * HDIM + c);
  }
  __syncthreads();
  int cg = (threadIdx.x & 63) << 2;
  int rg = (threadIdx.x >> 6) << 2;
  float acc[4][4] = {};
  const float* wp = w2 + cg;
  #pragma unroll 2
  for (int d = 0; d < HDIM; ++d){
    float4 wf = *(const float4*)(wp + d * DD);
    #pragma unroll
    for (int i = 0; i < 4; ++i){
      float hv = bf2f(hs[rg + i][d]);
      acc[i][0] += hv * wf.x; acc[i][1] += hv * wf.y;
      acc[i][2] += hv * wf.z; acc[i][3] += hv * wf.w;
    }
  }
  float4 bf = *(const float4*)(b2 + cg);
  for (int i = 0; i < 4; ++i){
    int row = tT + rg + i;
    float4 yr = *(const float4*)(y + row * DD + cg);
    float4 o = make_float4(acc[i][0] + bf.x + yr.x, acc[i][1] + bf.y + yr.y,
                           acc[i][2] + bf.z + yr.z, acc[i][3] + bf.w + yr.w);
    *(float4*)(x + row * DD + cg) = o;
  }
}

// ---------------- final LN + (256x32) projection, fp32 out ----------------
__global__ void __launch_bounds__(256) k_final(const float* __restrict__ x,
                                               const float* __restrict__ g,
                                               const float* __restrict__ b,
                                               const float* __restrict__ wout,
                                               const float* __restrict__ bout,
                                               float* __restrict__ out){
  __shared__ float lds[4][256];
  int widx = threadIdx.x >> 6, lane = threadIdx.x & 63;
  int bt = blockIdx.x * 4 + widx;
  float4 v = *(const float4*)(x + bt * DD + lane * 4);
  float s = v.x + v.y + v.z + v.w;
  float ss = v.x * v.x + v.y * v.y + v.z * v.z + v.w * v.w;
  #pragma unroll
  for (int o = 32; o; o >>= 1){ s += __shfl_xor(s, o, 64); ss += __shfl_xor(ss, o, 64); }
  float m = s * (1.0f / DD);
  float var = ss * (1.0f / DD) - m * m;
  float rs = rsqrtf(var + 1e-5f);
  float4 gf = *(const float4*)(g + lane * 4);
  float4 bf = *(const float4*)(b + lane * 4);
  lds[widx][lane * 4 + 0] = (v.x - m) * rs * gf.x + bf.x;
  lds[widx][lane * 4 + 1] = (v.y - m) * rs * gf.y + bf.y;
  lds[widx][lane * 4 + 2] = (v.z - m) * rs * gf.z + bf.z;
  lds[widx][lane * 4 + 3] = (v.w - m) * rs * gf.w + bf.w;
  __syncthreads();
  int vo = lane & 31, half = lane >> 5;
  const float* lp = &lds[widx][half * 128];
  const float* wp = wout + half * 128 * NVOCAB + vo;
  float acc = 0;
  #pragma unroll 4
  for (int d = 0; d < 128; ++d) acc += lp[d] * wp[d * NVOCAB];
  acc += __shfl_down(acc, 32, 64);
  if (lane < 32) out[bt * NVOCAB + vo] = acc + bout[vo];
}

extern "C" void kernel_launch(void* const* d_in, const int* in_sizes, int n_in,
                              void* d_out, int out_size, void* d_ws, size_t ws_size,
                              hipStream_t stream) {
  const int*   tokens = (const int*)d_in[0];
  const float* emb   = (const float*)d_in[1];
  const float* ffs   = (const float*)d_in[2];
  const float* ffb   = (const float*)d_in[3];
  const float* w1    = (const float*)d_in[4];
  const float* b1    = (const float*)d_in[5];
  const float* w2    = (const float*)d_in[6];
  const float* b2    = (const float*)d_in[7];
  const float* lnfs  = (const float*)d_in[8];
  const float* lnfb  = (const float*)d_in[9];
  const float* wout  = (const float*)d_in[10];
  const float* bout  = (const float*)d_in[11];
  float* out = (float*)d_out;

  char* ws = (char*)d_ws;
  float* x   = (float*)(ws);                         // 16 MB fp32
  float* y   = (float*)(ws + (size_t)16*1024*1024);  // 16 MB fp32
  u16*   lnx = (u16*)  (ws + (size_t)32*1024*1024);  //  8 MB bf16
  u16*   qk  = (u16*)  (ws + (size_t)40*1024*1024);  //  8 MB bf16
  u16*   h   = (u16*)  (ws + (size_t)48*1024*1024);  // 32 MB bf16
  float* ct  = (float*)(ws + (size_t)80*1024*1024);  //  4 MB
  float* st  = (float*)(ws + (size_t)84*1024*1024);  //  4 MB  (end: 88 MB)

  k_tables<<<4096, 256, 0, stream>>>(ct, st);
  k_embed<<<4096, 256, 0, stream>>>(tokens, emb, x);
  for (int L = 0; L < NLAYER; ++L){
    k_rope<<<2048, 256, 0, stream>>>(x, ct, st, qk);
    k_attn<<<4096, 256, 0, stream>>>(qk, x, y);
    k_ln  <<<4096, 256, 0, stream>>>(y, ffs + L*DD, ffb + L*DD, lnx);
    k_mm1 <<<dim3(8, 512), 256, 0, stream>>>(lnx, w1 + (size_t)L*DD*HDIM, b1 + L*HDIM, h);
    k_mm2 <<<1024, 256, 0, stream>>>(h, w2 + (size_t)L*HDIM*DD, b2 + L*DD, y, x);
  }
  k_final<<<4096, 256, 0, stream>>>(x, lnfs, lnfb, wout, bout, out);
}

// Round 3
// 2344.388 us; speedup vs baseline: 2.3319x; 2.3319x over previous
//
#include <hip/hip_runtime.h>
#include <hip/hip_bf16.h>
#include <math.h>

#define BATCH 2
#define SEQL 8192
#define DD 256
#define HDIM 1024
#define NLAYER 6
#define WSZ 512
#define NVOCAB 32

typedef unsigned short u16;
typedef __attribute__((ext_vector_type(8))) short bf16x8;
typedef __attribute__((ext_vector_type(4))) float f32x4;

union B8 { uint4 u; bf16x8 b; ushort s[8]; uint w[4]; };

__device__ inline float bf2f(u16 v){
  unsigned int u = ((unsigned int)v) << 16;
  return __uint_as_float(u);
}
__device__ inline u16 f2bf(float f){
  unsigned int u = __float_as_uint(f);
  u += 0x7fff + ((u >> 16) & 1);   // RNE
  return (u16)(u >> 16);
}
__device__ inline float4 bf4_to_f4(ushort4 v){
  return make_float4(bf2f(v.x), bf2f(v.y), bf2f(v.z), bf2f(v.w));
}

// ---------------- one-time rope tables (fp64 internally) ----------------
__global__ void k_tables(float* __restrict__ ct, float* __restrict__ st){
  int idx = blockIdx.x * 256 + threadIdx.x;     // t*128 + i
  if (idx >= SEQL * 128) return;
  int t = idx >> 7, i = idx & 127;
  double freq = exp(-((double)(2 * i) / (double)DD) * log(10000.0));
  double fr = (double)t * freq;
  ct[idx] = (float)cos(fr);
  st[idx] = (float)sin(fr);
}

// ---------------- embedding gather (fp32 table) ----------------
__global__ void k_embed(const int* __restrict__ tokens, const float* __restrict__ emb,
                        float* __restrict__ x){
  int idx = blockIdx.x * 256 + threadIdx.x;     // bt*64 + dvec
  int bt = idx >> 6, dv = (idx & 63) << 2;
  int tok = tokens[bt];
  *(float4*)(x + bt * DD + dv) = *(const float4*)(emb + tok * DD + dv);
}

// ------- rope: x(fp32) -> qk (roped bf16) and xv (plain bf16 copy) -------
__global__ void k_rope(const float* __restrict__ x, const float* __restrict__ ct,
                       const float* __restrict__ st, u16* __restrict__ qk,
                       u16* __restrict__ xv){
  int idx = blockIdx.x * 256 + threadIdx.x;     // bt*32 + ivec  (half-dim /4)
  int bt = idx >> 5, iv = (idx & 31) << 2;
  int t = bt & (SEQL - 1);
  const float* xr = x + bt * DD;
  float4 x1 = *(const float4*)(xr + iv);
  float4 x2 = *(const float4*)(xr + 128 + iv);
  float4 c = *(const float4*)(ct + t * 128 + iv);
  float4 s = *(const float4*)(st + t * 128 + iv);
  ushort4 q1, q2, v1, v2;
  q1.x = f2bf(x1.x * c.x - x2.x * s.x);  q2.x = f2bf(x2.x * c.x + x1.x * s.x);
  q1.y = f2bf(x1.y * c.y - x2.y * s.y);  q2.y = f2bf(x2.y * c.y + x1.y * s.y);
  q1.z = f2bf(x1.z * c.z - x2.z * s.z);  q2.z = f2bf(x2.z * c.z + x1.z * s.z);
  q1.w = f2bf(x1.w * c.w - x2.w * s.w);  q2.w = f2bf(x2.w * c.w + x1.w * s.w);
  v1.x = f2bf(x1.x); v1.y = f2bf(x1.y); v1.z = f2bf(x1.z); v1.w = f2bf(x1.w);
  v2.x = f2bf(x2.x); v2.y = f2bf(x2.y); v2.z = f2bf(x2.z); v2.w = f2bf(x2.w);
  *(ushort4*)(qk + bt * DD + iv)       = q1;
  *(ushort4*)(qk + bt * DD + 128 + iv) = q2;
  *(ushort4*)(xv + bt * DD + iv)       = v1;
  *(ushort4*)(xv + bt * DD + 128 + iv) = v2;
}

// ---------------- MFMA sliding-window attention ----------------
// 128 blocks x 512 threads. Block: 128 queries. Wave (qh,kh): 32 queries,
// key-half kh of each 64-key tile. Swapped QK^T (S^T = K·Q^T) so P^T->A-frag
// is a register-only repack. V staged transposed, frag-major. y = x + O/l.
__global__ void __launch_bounds__(512, 2) k_attn2(const u16* __restrict__ qk,
                                                  const u16* __restrict__ xv,
                                                  const float* __restrict__ x,
                                                  float* __restrict__ y){
  __shared__ char smem[65536];
  u16* Klds = (u16*)smem;               // 32 KB frag-major K tile
  u16* Vlds = (u16*)(smem + 32768);     // 32 KB frag-major V^T tile
  float* redbuf = (float*)smem;         // reused after main loop

  const int tid = threadIdx.x;
  const int lane = tid & 63;
  const int w = tid >> 6;
  const int qh = w >> 1, kh = w & 1;
  const int l15 = lane & 15, lg = lane >> 4;

  const int qb = blockIdx.x * 128;
  const int t0 = qb & (SEQL - 1);
  const size_t bbase = (size_t)(qb >> 13) << 13;

  // ---- preload Q B-frags: qf[qt][s] ----
  uint4 qf[2][8];
  #pragma unroll
  for (int qt = 0; qt < 2; ++qt){
    const u16* qr = qk + (size_t)(qb + qh*32 + qt*16 + l15) * DD + lg*4;
    #pragma unroll
    for (int s = 0; s < 8; ++s){
      uint2 a = *(const uint2*)(qr + s*32);
      uint2 b = *(const uint2*)(qr + s*32 + 16);
      qf[qt][s] = make_uint4(a.x, a.y, b.x, b.y);
    }
  }

  f32x4 oacc[2][16];
  #pragma unroll
  for (int qt = 0; qt < 2; ++qt)
    #pragma unroll
    for (int d = 0; d < 16; ++d)
      oacc[qt][d] = (f32x4){0.f, 0.f, 0.f, 0.f};
  float lacc0 = 0.f, lacc1 = 0.f;

  const int p0 = (t0 >= WSZ) ? (t0 - WSZ) : 0;
  const int ntile = ((t0 - p0) >> 6) + 2;

  // staging decompositions
  const int sk15 = tid & 15, skt = (tid >> 4) & 3, sc = tid >> 6;   // K stage
  const int sdh = tid & 31, sk0 = (tid >> 5) * 4;                   // V stage
  const int vkhw = sk0 >> 5, vh = (sk0 >> 4) & 1, vlgw = (sk0 >> 2) & 3;

  for (int ti = 0; ti < ntile; ++ti){
    const int p = p0 + ti*64;
    const size_t Kr = bbase + (size_t)p;

    // --- stage K tile (frag-major records of 16B) ---
    {
      const u16* sb = qk + (Kr + skt*16 + sk15) * DD;
      #pragma unroll
      for (int u = 0; u < 4; ++u){
        int d0 = u*64 + sc*8;
        uint4 v = *(const uint4*)(sb + d0);
        int s = d0 >> 5, r = d0 & 31;
        int h = r >> 4, lgw = (r & 15) >> 2;
        int rec = ((s*4 + skt)*4 + lgw)*16 + sk15;
        char* wp = (char*)Klds + rec*16 + h*8;
        *(uint2*)wp          = make_uint2(v.x, v.y);   // dims d0..d0+3
        *(uint2*)(wp + 256)  = make_uint2(v.z, v.w);   // dims d0+4..d0+7 (lg+1)
      }
    }
    // --- stage V^T tile (4-key transpose repack) ---
    {
      #pragma unroll
      for (int u = 0; u < 4; ++u){
        int d0 = sdh*2 + u*64;
        const u16* sb = xv + (Kr + sk0) * DD + d0;
        uint a0 = *(const uint*)(sb);
        uint a1 = *(const uint*)(sb + DD);
        uint a2 = *(const uint*)(sb + 2*DD);
        uint a3 = *(const uint*)(sb + 3*DD);
        uint w0 = (a0 & 0xffffu) | (a1 << 16);
        uint w1 = (a2 & 0xffffu) | (a3 << 16);
        uint w2 = (a0 >> 16) | (a1 & 0xffff0000u);
        uint w3 = (a2 >> 16) | (a3 & 0xffff0000u);
        int dimt = d0 >> 4, d15 = d0 & 15;
        int rec = ((dimt*2 + vkhw)*4 + vlgw)*16 + d15;
        char* wp = (char*)Vlds + rec*16 + vh*8;
        *(uint2*)wp        = make_uint2(w0, w1);   // dim d0,   keys k0..k0+3
        *(uint2*)(wp + 16) = make_uint2(w2, w3);   // dim d0+1
      }
    }
    __syncthreads();

    // --- S^T = K · Q^T over 8 d-steps ---
    f32x4 sacc[2][2];
    #pragma unroll
    for (int a = 0; a < 2; ++a){
      sacc[a][0] = (f32x4){0.f,0.f,0.f,0.f};
      sacc[a][1] = (f32x4){0.f,0.f,0.f,0.f};
    }
    #pragma unroll
    for (int s = 0; s < 8; ++s){
      B8 ka0, ka1, qb0, qb1;
      ka0.b = *(const bf16x8*)((char*)Klds + (((s*4 + kh*2+0)*4 + lg)*16 + l15)*16);
      ka1.b = *(const bf16x8*)((char*)Klds + (((s*4 + kh*2+1)*4 + lg)*16 + l15)*16);
      qb0.u = qf[0][s]; qb1.u = qf[1][s];
      sacc[0][0] = __builtin_amdgcn_mfma_f32_16x16x32_bf16(ka0.b, qb0.b, sacc[0][0], 0, 0, 0);
      sacc[0][1] = __builtin_amdgcn_mfma_f32_16x16x32_bf16(ka0.b, qb1.b, sacc[0][1], 0, 0, 0);
      sacc[1][0] = __builtin_amdgcn_mfma_f32_16x16x32_bf16(ka1.b, qb0.b, sacc[1][0], 0, 0, 0);
      sacc[1][1] = __builtin_amdgcn_mfma_f32_16x16x32_bf16(ka1.b, qb1.b, sacc[1][1], 0, 0, 0);
    }

    // --- mask + exp + pack P^T -> PV A-frags (register-only) ---
    B8 pa0, pa1;
    #pragma unroll
    for (int ktp = 0; ktp < 2; ++ktp){
      int kbase = p + kh*32 + ktp*16 + lg*4;
      #pragma unroll
      for (int r = 0; r < 4; ++r){
        int kpos = kbase + r;
        int qpos0 = t0 + qh*32 + l15;
        int qpos1 = qpos0 + 16;
        float sv0 = sacc[ktp][0][r] * 0.0625f;
        float sv1 = sacc[ktp][1][r] * 0.0625f;
        bool ok0 = (kpos <= qpos0) && (qpos0 <= kpos + WSZ);
        bool ok1 = (kpos <= qpos1) && (qpos1 <= kpos + WSZ);
        float pv0 = ok0 ? __expf(sv0) : 0.0f;
        float pv1 = ok1 ? __expf(sv1) : 0.0f;
        lacc0 += pv0;
        lacc1 += pv1;
        pa0.s[ktp*4 + r] = f2bf(pv0);
        pa1.s[ktp*4 + r] = f2bf(pv1);
      }
    }

    // --- O += P · V ---
    #pragma unroll
    for (int dimt = 0; dimt < 16; ++dimt){
      B8 vb;
      vb.b = *(const bf16x8*)((char*)Vlds + (((dimt*2 + kh)*4 + lg)*16 + l15)*16);
      oacc[0][dimt] = __builtin_amdgcn_mfma_f32_16x16x32_bf16(pa0.b, vb.b, oacc[0][dimt], 0, 0, 0);
      oacc[1][dimt] = __builtin_amdgcn_mfma_f32_16x16x32_bf16(pa1.b, vb.b, oacc[1][dimt], 0, 0, 0);
    }
    __syncthreads();
  }

  // ---- combine kh halves + normalize + residual ----
  lacc0 += __shfl_xor(lacc0, 16, 64);  lacc0 += __shfl_xor(lacc0, 32, 64);
  lacc1 += __shfl_xor(lacc1, 16, 64);  lacc1 += __shfl_xor(lacc1, 32, 64);
  if (lane < 16){
    redbuf[kh*128 + qh*32 + l15]      = lacc0;
    redbuf[kh*128 + qh*32 + 16 + l15] = lacc1;
  }
  __syncthreads();
  if (tid < 128) redbuf[256 + tid] = redbuf[tid] + redbuf[128 + tid];
  __syncthreads();

  float* opass = redbuf + 384;        // [2][128][32] fp32 per pass
  #pragma unroll
  for (int pass = 0; pass < 8; ++pass){
    #pragma unroll
    for (int qt = 0; qt < 2; ++qt){
      #pragma unroll
      for (int dt = 0; dt < 2; ++dt){
        int dimt = pass*2 + dt;
        #pragma unroll
        for (int r = 0; r < 4; ++r){
          int qrow = qh*32 + qt*16 + lg*4 + r;
          opass[kh*4096 + qrow*32 + dt*16 + l15] = oacc[qt][dimt][r];
        }
      }
    }
    __syncthreads();
    #pragma unroll
    for (int c = 0; c < 2; ++c){
      int fi = c*512 + tid;
      int q = fi >> 3, dv = (fi & 7) * 4;
      float4 o0 = *(float4*)&opass[q*32 + dv];
      float4 o1 = *(float4*)&opass[4096 + q*32 + dv];
      float inv = 1.0f / redbuf[256 + q];
      size_t gi = (size_t)(qb + q) * DD + pass*32 + dv;
      float4 xr = *(const float4*)(x + gi);
      float4 ov;
      ov.x = xr.x + (o0.x + o1.x) * inv;
      ov.y = xr.y + (o0.y + o1.y) * inv;
      ov.z = xr.z + (o0.z + o1.z) * inv;
      ov.w = xr.w + (o0.w + o1.w) * inv;
      *(float4*)(y + gi) = ov;
    }
    __syncthreads();
  }
}

// ---------------- layernorm (wave per token), fp32 in, bf16 out ----------------
__global__ void __launch_bounds__(256) k_ln(const float* __restrict__ in,
                                            const float* __restrict__ g,
                                            const float* __restrict__ b,
                                            u16* __restrict__ out){
  int wid = (blockIdx.x * 256 + threadIdx.x) >> 6;
  int lane = threadIdx.x & 63;
  float4 v = *(const float4*)(in + wid * DD + lane * 4);
  float s = v.x + v.y + v.z + v.w;
  float ss = v.x * v.x + v.y * v.y + v.z * v.z + v.w * v.w;
  #pragma unroll
  for (int o = 32; o; o >>= 1){ s += __shfl_xor(s, o, 64); ss += __shfl_xor(ss, o, 64); }
  float m = s * (1.0f / DD);
  float var = ss * (1.0f / DD) - m * m;
  float rs = rsqrtf(var + 1e-5f);
  float4 gf = *(const float4*)(g + lane * 4);
  float4 bf = *(const float4*)(b + lane * 4);
  ushort4 o4;
  o4.x = f2bf((v.x - m) * rs * gf.x + bf.x);
  o4.y = f2bf((v.y - m) * rs * gf.y + bf.y);
  o4.z = f2bf((v.z - m) * rs * gf.z + bf.z);
  o4.w = f2bf((v.w - m) * rs * gf.w + bf.w);
  *(ushort4*)(out + wid * DD + lane * 4) = o4;
}

// ---------------- mm1 + bias + exact gelu: (16384x256)@(256x1024) -> h bf16 ----
__global__ void __launch_bounds__(256) k_mm1(const u16* __restrict__ lnx,
                                             const float* __restrict__ w1,
                                             const float* __restrict__ b1,
                                             u16* __restrict__ h){
  __shared__ u16 xs[32][264];
  int tT = blockIdx.y * 32;
  int cB = blockIdx.x * 128;
  for (int i = threadIdx.x; i < 32 * 64; i += 256){
    int r = i >> 6, c = (i & 63) << 2;
    *(ushort4*)&xs[r][c] = *(const ushort4*)(lnx + (tT + r) * DD + c);
  }
  __syncthreads();
  int cg = (threadIdx.x & 31) << 2;
  int rg = (threadIdx.x >> 5) << 2;
  float acc[4][4] = {};
  const float* wp = w1 + cB + cg;
  #pragma unroll 2
  for (int d = 0; d < DD; ++d){
    float4 wf = *(const float4*)(wp + d * HDIM);
    #pragma unroll
    for (int i = 0; i < 4; ++i){
      float xvv = bf2f(xs[rg + i][d]);
      acc[i][0] += xvv * wf.x; acc[i][1] += xvv * wf.y;
      acc[i][2] += xvv * wf.z; acc[i][3] += xvv * wf.w;
    }
  }
  float4 bf = *(const float4*)(b1 + cB + cg);
  float bias[4] = {bf.x, bf.y, bf.z, bf.w};
  for (int i = 0; i < 4; ++i){
    ushort4 o; u16* po = (u16*)&o;
    #pragma unroll
    for (int j = 0; j < 4; ++j){
      float v = acc[i][j] + bias[j];
      v = 0.5f * v * (1.0f + erff(v * 0.70710678f));
      po[j] = f2bf(v);
    }
    *(ushort4*)(h + (size_t)(tT + rg + i) * HDIM + cB + cg) = o;
  }
}

// ---------------- mm2 + bias + residual: (16384x1024)@(1024x256) + y -> x fp32 --
__global__ void __launch_bounds__(256) k_mm2(const u16* __restrict__ h,
                                             const float* __restrict__ w2,
                                             const float* __restrict__ b2,
                                             const float* __restrict__ y,
                                             float* __restrict__ x){
  __shared__ u16 hs[16][1032];
  int tT = blockIdx.x * 16;
  for (int i = threadIdx.x; i < 16 * 256; i += 256){
    int r = i >> 8, c = (i & 255) << 2;
    *(ushort4*)&hs[r][c] = *(const ushort4*)(h + (size_t)(tT + r) * HDIM + c);
  }
  __syncthreads();
  int cg = (threadIdx.x & 63) << 2;
  int rg = (threadIdx.x >> 6) << 2;
  float acc[4][4] = {};
  const float* wp = w2 + cg;
  #pragma unroll 2
  for (int d = 0; d < HDIM; ++d){
    float4 wf = *(const float4*)(wp + d * DD);
    #pragma unroll
    for (int i = 0; i < 4; ++i){
      float hv = bf2f(hs[rg + i][d]);
      acc[i][0] += hv * wf.x; acc[i][1] += hv * wf.y;
      acc[i][2] += hv * wf.z; acc[i][3] += hv * wf.w;
    }
  }
  float4 bf = *(const float4*)(b2 + cg);
  for (int i = 0; i < 4; ++i){
    int row = tT + rg + i;
    float4 yr = *(const float4*)(y + row * DD + cg);
    float4 o = make_float4(acc[i][0] + bf.x + yr.x, acc[i][1] + bf.y + yr.y,
                           acc[i][2] + bf.z + yr.z, acc[i][3] + bf.w + yr.w);
    *(float4*)(x + row * DD + cg) = o;
  }
}

// ---------------- final LN + (256x32) projection, fp32 out ----------------
__global__ void __launch_bounds__(256) k_final(const float* __restrict__ x,
                                               const float* __restrict__ g,
                                               const float* __restrict__ b,
                                               const float* __restrict__ wout,
                                               const float* __restrict__ bout,
                                               float* __restrict__ out){
  __shared__ float lds[4][256];
  int widx = threadIdx.x >> 6, lane = threadIdx.x & 63;
  int bt = blockIdx.x * 4 + widx;
  float4 v = *(const float4*)(x + bt * DD + lane * 4);
  float s = v.x + v.y + v.z + v.w;
  float ss = v.x * v.x + v.y * v.y + v.z * v.z + v.w * v.w;
  #pragma unroll
  for (int o = 32; o; o >>= 1){ s += __shfl_xor(s, o, 64); ss += __shfl_xor(ss, o, 64); }
  float m = s * (1.0f / DD);
  float var = ss * (1.0f / DD) - m * m;
  float rs = rsqrtf(var + 1e-5f);
  float4 gf = *(const float4*)(g + lane * 4);
  float4 bf = *(const float4*)(b + lane * 4);
  lds[widx][lane * 4 + 0] = (v.x - m) * rs * gf.x + bf.x;
  lds[widx][lane * 4 + 1] = (v.y - m) * rs * gf.y + bf.y;
  lds[widx][lane * 4 + 2] = (v.z - m) * rs * gf.z + bf.z;
  lds[widx][lane * 4 + 3] = (v.w - m) * rs * gf.w + bf.w;
  __syncthreads();
  int vo = lane & 31, half = lane >> 5;
  const float* lp = &lds[widx][half * 128];
  const float* wp = wout + half * 128 * NVOCAB + vo;
  float acc = 0;
  #pragma unroll 4
  for (int d = 0; d < 128; ++d) acc += lp[d] * wp[d * NVOCAB];
  acc += __shfl_down(acc, 32, 64);
  if (lane < 32) out[bt * NVOCAB + vo] = acc + bout[vo];
}

extern "C" void kernel_launch(void* const* d_in, const int* in_sizes, int n_in,
                              void* d_out, int out_size, void* d_ws, size_t ws_size,
                              hipStream_t stream) {
  const int*   tokens = (const int*)d_in[0];
  const float* emb   = (const float*)d_in[1];
  const float* ffs   = (const float*)d_in[2];
  const float* ffb   = (const float*)d_in[3];
  const float* w1    = (const float*)d_in[4];
  const float* b1    = (const float*)d_in[5];
  const float* w2    = (const float*)d_in[6];
  const float* b2    = (const float*)d_in[7];
  const float* lnfs  = (const float*)d_in[8];
  const float* lnfb  = (const float*)d_in[9];
  const float* wout  = (const float*)d_in[10];
  const float* bout  = (const float*)d_in[11];
  float* out = (float*)d_out;

  char* ws = (char*)d_ws;
  float* x    = (float*)(ws);                         // 16 MB fp32
  float* y    = (float*)(ws + (size_t)16*1024*1024);  // 16 MB fp32
  u16*   buf8 = (u16*)  (ws + (size_t)32*1024*1024);  //  8 MB bf16 (xv then lnx)
  u16*   qk   = (u16*)  (ws + (size_t)40*1024*1024);  //  8 MB bf16
  u16*   h    = (u16*)  (ws + (size_t)48*1024*1024);  // 32 MB bf16
  float* ct   = (float*)(ws + (size_t)80*1024*1024);  //  4 MB
  float* st   = (float*)(ws + (size_t)84*1024*1024);  //  4 MB  (end: 88 MB)

  k_tables<<<4096, 256, 0, stream>>>(ct, st);
  k_embed<<<4096, 256, 0, stream>>>(tokens, emb, x);
  for (int L = 0; L < NLAYER; ++L){
    k_rope<<<2048, 256, 0, stream>>>(x, ct, st, qk, buf8);
    k_attn2<<<128, 512, 0, stream>>>(qk, buf8, x, y);
    k_ln  <<<4096, 256, 0, stream>>>(y, ffs + L*DD, ffb + L*DD, buf8);
    k_mm1 <<<dim3(8, 512), 256, 0, stream>>>(buf8, w1 + (size_t)L*DD*HDIM, b1 + L*HDIM, h);
    k_mm2 <<<1024, 256, 0, stream>>>(h, w2 + (size_t)L*HDIM*DD, b2 + L*DD, y, x);
  }
  k_final<<<4096, 256, 0, stream>>>(x, lnfs, lnfb, wout, bout, out);
}

// Round 5
// 895.999 us; speedup vs baseline: 6.1015x; 2.6165x over previous
//
#include <hip/hip_runtime.h>
#include <hip/hip_bf16.h>
#include <math.h>

#define BATCH 2
#define SEQL 8192
#define DD 256
#define HDIM 1024
#define NLAYER 6
#define WSZ 512
#define NVOCAB 32

typedef unsigned short u16;
typedef __attribute__((ext_vector_type(8))) short bf16x8;
typedef __attribute__((ext_vector_type(4))) float f32x4;

union B8 { uint4 u; bf16x8 b; ushort s[8]; uint w[4]; };

__device__ inline float bf2f(u16 v){
  unsigned int u = ((unsigned int)v) << 16;
  return __uint_as_float(u);
}
__device__ inline u16 f2bf(float f){
  unsigned int u = __float_as_uint(f);
  u += 0x7fff + ((u >> 16) & 1);   // RNE
  return (u16)(u >> 16);
}
__device__ inline float4 bf4_to_f4(ushort4 v){
  return make_float4(bf2f(v.x), bf2f(v.y), bf2f(v.z), bf2f(v.w));
}

// ---------------- one-time rope tables (fp64 internally) ----------------
__global__ void k_tables(float* __restrict__ ct, float* __restrict__ st){
  int idx = blockIdx.x * 256 + threadIdx.x;     // t*128 + i
  if (idx >= SEQL * 128) return;
  int t = idx >> 7, i = idx & 127;
  double freq = exp(-((double)(2 * i) / (double)DD) * log(10000.0));
  double fr = (double)t * freq;
  ct[idx] = (float)cos(fr);
  st[idx] = (float)sin(fr);
}

// ---------------- embedding gather (fp32 table) ----------------
__global__ void k_embed(const int* __restrict__ tokens, const float* __restrict__ emb,
                        float* __restrict__ x){
  int idx = blockIdx.x * 256 + threadIdx.x;     // bt*64 + dvec
  int bt = idx >> 6, dv = (idx & 63) << 2;
  int tok = tokens[bt];
  *(float4*)(x + bt * DD + dv) = *(const float4*)(emb + tok * DD + dv);
}

// ------- rope: x(fp32) -> qk (roped bf16) and xv (plain bf16 copy) -------
__global__ void k_rope(const float* __restrict__ x, const float* __restrict__ ct,
                       const float* __restrict__ st, u16* __restrict__ qk,
                       u16* __restrict__ xv){
  int idx = blockIdx.x * 256 + threadIdx.x;     // bt*32 + ivec  (half-dim /4)
  int bt = idx >> 5, iv = (idx & 31) << 2;
  int t = bt & (SEQL - 1);
  const float* xr = x + bt * DD;
  float4 x1 = *(const float4*)(xr + iv);
  float4 x2 = *(const float4*)(xr + 128 + iv);
  float4 c = *(const float4*)(ct + t * 128 + iv);
  float4 s = *(const float4*)(st + t * 128 + iv);
  ushort4 q1, q2, v1, v2;
  q1.x = f2bf(x1.x * c.x - x2.x * s.x);  q2.x = f2bf(x2.x * c.x + x1.x * s.x);
  q1.y = f2bf(x1.y * c.y - x2.y * s.y);  q2.y = f2bf(x2.y * c.y + x1.y * s.y);
  q1.z = f2bf(x1.z * c.z - x2.z * s.z);  q2.z = f2bf(x2.z * c.z + x1.z * s.z);
  q1.w = f2bf(x1.w * c.w - x2.w * s.w);  q2.w = f2bf(x2.w * c.w + x1.w * s.w);
  v1.x = f2bf(x1.x); v1.y = f2bf(x1.y); v1.z = f2bf(x1.z); v1.w = f2bf(x1.w);
  v2.x = f2bf(x2.x); v2.y = f2bf(x2.y); v2.z = f2bf(x2.z); v2.w = f2bf(x2.w);
  *(ushort4*)(qk + bt * DD + iv)       = q1;
  *(ushort4*)(qk + bt * DD + 128 + iv) = q2;
  *(ushort4*)(xv + bt * DD + iv)       = v1;
  *(ushort4*)(xv + bt * DD + 128 + iv) = v2;
}

// ---------------- MFMA sliding-window attention (unchanged from round 3) ------
__global__ void __launch_bounds__(512, 2) k_attn2(const u16* __restrict__ qk,
                                                  const u16* __restrict__ xv,
                                                  const float* __restrict__ x,
                                                  float* __restrict__ y){
  __shared__ char smem[65536];
  u16* Klds = (u16*)smem;               // 32 KB frag-major K tile
  u16* Vlds = (u16*)(smem + 32768);     // 32 KB frag-major V^T tile
  float* redbuf = (float*)smem;         // reused after main loop

  const int tid = threadIdx.x;
  const int lane = tid & 63;
  const int w = tid >> 6;
  const int qh = w >> 1, kh = w & 1;
  const int l15 = lane & 15, lg = lane >> 4;

  const int qb = blockIdx.x * 128;
  const int t0 = qb & (SEQL - 1);
  const size_t bbase = (size_t)(qb >> 13) << 13;

  uint4 qf[2][8];
  #pragma unroll
  for (int qt = 0; qt < 2; ++qt){
    const u16* qr = qk + (size_t)(qb + qh*32 + qt*16 + l15) * DD + lg*4;
    #pragma unroll
    for (int s = 0; s < 8; ++s){
      uint2 a = *(const uint2*)(qr + s*32);
      uint2 b = *(const uint2*)(qr + s*32 + 16);
      qf[qt][s] = make_uint4(a.x, a.y, b.x, b.y);
    }
  }

  f32x4 oacc[2][16];
  #pragma unroll
  for (int qt = 0; qt < 2; ++qt)
    #pragma unroll
    for (int d = 0; d < 16; ++d)
      oacc[qt][d] = (f32x4){0.f, 0.f, 0.f, 0.f};
  float lacc0 = 0.f, lacc1 = 0.f;

  const int p0 = (t0 >= WSZ) ? (t0 - WSZ) : 0;
  const int ntile = ((t0 - p0) >> 6) + 2;

  const int sk15 = tid & 15, skt = (tid >> 4) & 3, sc = tid >> 6;   // K stage
  const int sdh = tid & 31, sk0 = (tid >> 5) * 4;                   // V stage
  const int vkhw = sk0 >> 5, vh = (sk0 >> 4) & 1, vlgw = (sk0 >> 2) & 3;

  for (int ti = 0; ti < ntile; ++ti){
    const int p = p0 + ti*64;
    const size_t Kr = bbase + (size_t)p;

    {
      const u16* sb = qk + (Kr + skt*16 + sk15) * DD;
      #pragma unroll
      for (int u = 0; u < 4; ++u){
        int d0 = u*64 + sc*8;
        uint4 v = *(const uint4*)(sb + d0);
        int s = d0 >> 5, r = d0 & 31;
        int h = r >> 4, lgw = (r & 15) >> 2;
        int rec = ((s*4 + skt)*4 + lgw)*16 + sk15;
        char* wp = (char*)Klds + rec*16 + h*8;
        *(uint2*)wp          = make_uint2(v.x, v.y);
        *(uint2*)(wp + 256)  = make_uint2(v.z, v.w);
      }
    }
    {
      #pragma unroll
      for (int u = 0; u < 4; ++u){
        int d0 = sdh*2 + u*64;
        const u16* sb = xv + (Kr + sk0) * DD + d0;
        uint a0 = *(const uint*)(sb);
        uint a1 = *(const uint*)(sb + DD);
        uint a2 = *(const uint*)(sb + 2*DD);
        uint a3 = *(const uint*)(sb + 3*DD);
        uint w0 = (a0 & 0xffffu) | (a1 << 16);
        uint w1 = (a2 & 0xffffu) | (a3 << 16);
        uint w2 = (a0 >> 16) | (a1 & 0xffff0000u);
        uint w3 = (a2 >> 16) | (a3 & 0xffff0000u);
        int dimt = d0 >> 4, d15 = d0 & 15;
        int rec = ((dimt*2 + vkhw)*4 + vlgw)*16 + d15;
        char* wp = (char*)Vlds + rec*16 + vh*8;
        *(uint2*)wp        = make_uint2(w0, w1);
        *(uint2*)(wp + 16) = make_uint2(w2, w3);
      }
    }
    __syncthreads();

    f32x4 sacc[2][2];
    #pragma unroll
    for (int a = 0; a < 2; ++a){
      sacc[a][0] = (f32x4){0.f,0.f,0.f,0.f};
      sacc[a][1] = (f32x4){0.f,0.f,0.f,0.f};
    }
    #pragma unroll
    for (int s = 0; s < 8; ++s){
      B8 ka0, ka1, qb0, qb1;
      ka0.b = *(const bf16x8*)((char*)Klds + (((s*4 + kh*2+0)*4 + lg)*16 + l15)*16);
      ka1.b = *(const bf16x8*)((char*)Klds + (((s*4 + kh*2+1)*4 + lg)*16 + l15)*16);
      qb0.u = qf[0][s]; qb1.u = qf[1][s];
      sacc[0][0] = __builtin_amdgcn_mfma_f32_16x16x32_bf16(ka0.b, qb0.b, sacc[0][0], 0, 0, 0);
      sacc[0][1] = __builtin_amdgcn_mfma_f32_16x16x32_bf16(ka0.b, qb1.b, sacc[0][1], 0, 0, 0);
      sacc[1][0] = __builtin_amdgcn_mfma_f32_16x16x32_bf16(ka1.b, qb0.b, sacc[1][0], 0, 0, 0);
      sacc[1][1] = __builtin_amdgcn_mfma_f32_16x16x32_bf16(ka1.b, qb1.b, sacc[1][1], 0, 0, 0);
    }

    B8 pa0, pa1;
    #pragma unroll
    for (int ktp = 0; ktp < 2; ++ktp){
      int kbase = p + kh*32 + ktp*16 + lg*4;
      #pragma unroll
      for (int r = 0; r < 4; ++r){
        int kpos = kbase + r;
        int qpos0 = t0 + qh*32 + l15;
        int qpos1 = qpos0 + 16;
        float sv0 = sacc[ktp][0][r] * 0.0625f;
        float sv1 = sacc[ktp][1][r] * 0.0625f;
        bool ok0 = (kpos <= qpos0) && (qpos0 <= kpos + WSZ);
        bool ok1 = (kpos <= qpos1) && (qpos1 <= kpos + WSZ);
        float pv0 = ok0 ? __expf(sv0) : 0.0f;
        float pv1 = ok1 ? __expf(sv1) : 0.0f;
        lacc0 += pv0;
        lacc1 += pv1;
        pa0.s[ktp*4 + r] = f2bf(pv0);
        pa1.s[ktp*4 + r] = f2bf(pv1);
      }
    }

    #pragma unroll
    for (int dimt = 0; dimt < 16; ++dimt){
      B8 vb;
      vb.b = *(const bf16x8*)((char*)Vlds + (((dimt*2 + kh)*4 + lg)*16 + l15)*16);
      oacc[0][dimt] = __builtin_amdgcn_mfma_f32_16x16x32_bf16(pa0.b, vb.b, oacc[0][dimt], 0, 0, 0);
      oacc[1][dimt] = __builtin_amdgcn_mfma_f32_16x16x32_bf16(pa1.b, vb.b, oacc[1][dimt], 0, 0, 0);
    }
    __syncthreads();
  }

  lacc0 += __shfl_xor(lacc0, 16, 64);  lacc0 += __shfl_xor(lacc0, 32, 64);
  lacc1 += __shfl_xor(lacc1, 16, 64);  lacc1 += __shfl_xor(lacc1, 32, 64);
  if (lane < 16){
    redbuf[kh*128 + qh*32 + l15]      = lacc0;
    redbuf[kh*128 + qh*32 + 16 + l15] = lacc1;
  }
  __syncthreads();
  if (tid < 128) redbuf[256 + tid] = redbuf[tid] + redbuf[128 + tid];
  __syncthreads();

  float* opass = redbuf + 384;
  #pragma unroll
  for (int pass = 0; pass < 8; ++pass){
    #pragma unroll
    for (int qt = 0; qt < 2; ++qt){
      #pragma unroll
      for (int dt = 0; dt < 2; ++dt){
        int dimt = pass*2 + dt;
        #pragma unroll
        for (int r = 0; r < 4; ++r){
          int qrow = qh*32 + qt*16 + lg*4 + r;
          opass[kh*4096 + qrow*32 + dt*16 + l15] = oacc[qt][dimt][r];
        }
      }
    }
    __syncthreads();
    #pragma unroll
    for (int c = 0; c < 2; ++c){
      int fi = c*512 + tid;
      int q = fi >> 3, dv = (fi & 7) * 4;
      float4 o0 = *(float4*)&opass[q*32 + dv];
      float4 o1 = *(float4*)&opass[4096 + q*32 + dv];
      float inv = 1.0f / redbuf[256 + q];
      size_t gi = (size_t)(qb + q) * DD + pass*32 + dv;
      float4 xr = *(const float4*)(x + gi);
      float4 ov;
      ov.x = xr.x + (o0.x + o1.x) * inv;
      ov.y = xr.y + (o0.y + o1.y) * inv;
      ov.z = xr.z + (o0.z + o1.z) * inv;
      ov.w = xr.w + (o0.w + o1.w) * inv;
      *(float4*)(y + gi) = ov;
    }
    __syncthreads();
  }
}

// ---------------- layernorm (wave per token), fp32 in, bf16 out ----------------
__global__ void __launch_bounds__(256) k_ln(const float* __restrict__ in,
                                            const float* __restrict__ g,
                                            const float* __restrict__ b,
                                            u16* __restrict__ out){
  int wid = (blockIdx.x * 256 + threadIdx.x) >> 6;
  int lane = threadIdx.x & 63;
  float4 v = *(const float4*)(in + wid * DD + lane * 4);
  float s = v.x + v.y + v.z + v.w;
  float ss = v.x * v.x + v.y * v.y + v.z * v.z + v.w * v.w;
  #pragma unroll
  for (int o = 32; o; o >>= 1){ s += __shfl_xor(s, o, 64); ss += __shfl_xor(ss, o, 64); }
  float m = s * (1.0f / DD);
  float var = ss * (1.0f / DD) - m * m;
  float rs = rsqrtf(var + 1e-5f);
  float4 gf = *(const float4*)(g + lane * 4);
  float4 bf = *(const float4*)(b + lane * 4);
  ushort4 o4;
  o4.x = f2bf((v.x - m) * rs * gf.x + bf.x);
  o4.y = f2bf((v.y - m) * rs * gf.y + bf.y);
  o4.z = f2bf((v.z - m) * rs * gf.z + bf.z);
  o4.w = f2bf((v.w - m) * rs * gf.w + bf.w);
  *(ushort4*)(out + wid * DD + lane * 4) = o4;
}

// -------- weight split: fp32 W[K][N] -> frag-major hi/lo bf16 planes ----------
// record idx = ((ks*(N/16) + nt)*4 + lg)*16 + c15; 8 bf16 per record:
// j=0..3: k = ks*32+lg*4+j ; j=4..7: k = ks*32+16+lg*4+(j-4); col = nt*16+c15
template<int KDIM, int NDIM>
__global__ void __launch_bounds__(256) k_split(const float* __restrict__ W,
                                               u16* __restrict__ Phi,
                                               u16* __restrict__ Plo){
  int idx = blockIdx.x * 256 + threadIdx.x;   // [0, KDIM*NDIM/8)
  int c15 = idx & 15;
  int lg = (idx >> 4) & 3;
  int nt = (idx >> 6) % (NDIM/16);
  int ks = idx / ((NDIM/16) * 64);
  int col = nt*16 + c15;
  B8 hi, lo;
  #pragma unroll
  for (int j = 0; j < 8; ++j){
    int k = ks*32 + (j >> 2)*16 + lg*4 + (j & 3);
    float wv = W[(size_t)k * NDIM + col];
    u16 hv = f2bf(wv);
    hi.s[j] = hv;
    lo.s[j] = f2bf(wv - bf2f(hv));
  }
  *(uint4*)(Phi + (size_t)idx * 8) = hi.u;
  *(uint4*)(Plo + (size_t)idx * 8) = lo.u;
}

// ---------------- MFMA GEMM: C = A(bf16) @ (hi+lo planes) ----------------
// BM=BN=128, BK=64, 4 waves (2x2), 64x64/wave. EPI 0: bias+GELU -> bf16 h.
// EPI 1: bias + residual -> fp32 x.
template<int KDIM, int NDIM, int EPI>
__global__ void __launch_bounds__(256) k_gemm(const u16* __restrict__ A,
                                              const u16* __restrict__ BhG,
                                              const u16* __restrict__ BlG,
                                              const float* __restrict__ bias,
                                              const float* __restrict__ res,
                                              float* __restrict__ outf,
                                              u16* __restrict__ outh){
  __shared__ char smem[51200];
  char* As = smem;                            // [128][144B] padded row-major
  char* Bh = smem + 18432;                    // 16 KB frag-major hi
  char* Bl = smem + 34816;                    // 16 KB frag-major lo

  const int tid = threadIdx.x;
  const int lane = tid & 63;
  const int w = tid >> 6;
  const int wr = w >> 1, wc = w & 1;
  const int l15 = lane & 15, lg = lane >> 4;
  const int m0 = blockIdx.y * 128;
  const int n0 = blockIdx.x * 128;

  f32x4 acc[4][4];
  #pragma unroll
  for (int a = 0; a < 4; ++a)
    #pragma unroll
    for (int c = 0; c < 4; ++c)
      acc[a][c] = (f32x4){0.f,0.f,0.f,0.f};

  for (int kb = 0; kb < KDIM/64; ++kb){
    __syncthreads();
    // stage A tile [128][64] bf16 -> 144B-stride rows
    #pragma unroll
    for (int p = 0; p < 4; ++p){
      int c = p*256 + tid;
      int row = c >> 3, cc = c & 7;
      uint4 v = *(const uint4*)(A + (size_t)(m0 + row) * KDIM + kb*64 + cc*8);
      *(uint4*)(As + row*144 + cc*16) = v;
    }
    // stage B: contiguous copy of precomputed frag-major records
    #pragma unroll
    for (int s = 0; s < 2; ++s){
      size_t gbase = ((size_t)(kb*2 + s) * (NDIM/16) + (n0 >> 4)) * 64;  // recs
      const uint4* srcH = (const uint4*)BhG + gbase;
      const uint4* srcL = (const uint4*)BlG + gbase;
      #pragma unroll
      for (int rr = 0; rr < 2; ++rr){
        int r = rr*256 + tid;
        *(uint4*)(Bh + (s*512 + r)*16) = srcH[r];
        *(uint4*)(Bl + (s*512 + r)*16) = srcL[r];
      }
    }
    __syncthreads();

    #pragma unroll
    for (int s = 0; s < 2; ++s){
      B8 af[4], bhf[4], blf[4];
      #pragma unroll
      for (int a = 0; a < 4; ++a){
        const char* ab = As + (wr*64 + a*16 + l15)*144 + s*64 + lg*8;
        uint2 lo = *(const uint2*)ab;
        uint2 hi = *(const uint2*)(ab + 32);
        af[a].u = make_uint4(lo.x, lo.y, hi.x, hi.y);
      }
      #pragma unroll
      for (int c = 0; c < 4; ++c){
        int rec = s*512 + (wc*4 + c)*64 + lg*16 + l15;
        bhf[c].u = *(const uint4*)(Bh + rec*16);
        blf[c].u = *(const uint4*)(Bl + rec*16);
      }
      #pragma unroll
      for (int a = 0; a < 4; ++a)
        #pragma unroll
        for (int c = 0; c < 4; ++c){
          acc[a][c] = __builtin_amdgcn_mfma_f32_16x16x32_bf16(af[a].b, bhf[c].b, acc[a][c], 0, 0, 0);
          acc[a][c] = __builtin_amdgcn_mfma_f32_16x16x32_bf16(af[a].b, blf[c].b, acc[a][c], 0, 0, 0);
        }
    }
  }

  // epilogue
  float bv[4];
  #pragma unroll
  for (int c = 0; c < 4; ++c) bv[c] = bias[n0 + wc*64 + c*16 + l15];

  #pragma unroll
  for (int a = 0; a < 4; ++a){
    #pragma unroll
    for (int c = 0; c < 4; ++c){
      #pragma unroll
      for (int r = 0; r < 4; ++r){
        int row = m0 + wr*64 + a*16 + lg*4 + r;
        int col = n0 + wc*64 + c*16 + l15;
        float v = acc[a][c][r] + bv[c];
        if (EPI == 0){
          float gl = 0.5f * v * (1.0f + erff(v * 0.70710678f));
          outh[(size_t)row * NDIM + col] = f2bf(gl);
        } else {
          outf[(size_t)row * NDIM + col] = v + res[(size_t)row * NDIM + col];
        }
      }
    }
  }
}

// ---------------- final LN + (256x32) projection, fp32 out ----------------
__global__ void __launch_bounds__(256) k_final(const float* __restrict__ x,
                                               const float* __restrict__ g,
                                               const float* __restrict__ b,
                                               const float* __restrict__ wout,
                                               const float* __restrict__ bout,
                                               float* __restrict__ out){
  __shared__ float lds[4][256];
  int widx = threadIdx.x >> 6, lane = threadIdx.x & 63;
  int bt = blockIdx.x * 4 + widx;
  float4 v = *(const float4*)(x + bt * DD + lane * 4);
  float s = v.x + v.y + v.z + v.w;
  float ss = v.x * v.x + v.y * v.y + v.z * v.z + v.w * v.w;
  #pragma unroll
  for (int o = 32; o; o >>= 1){ s += __shfl_xor(s, o, 64); ss += __shfl_xor(ss, o, 64); }
  float m = s * (1.0f / DD);
  float var = ss * (1.0f / DD) - m * m;
  float rs = rsqrtf(var + 1e-5f);
  float4 gf = *(const float4*)(g + lane * 4);
  float4 bf = *(const float4*)(b + lane * 4);
  lds[widx][lane * 4 + 0] = (v.x - m) * rs * gf.x + bf.x;
  lds[widx][lane * 4 + 1] = (v.y - m) * rs * gf.y + bf.y;
  lds[widx][lane * 4 + 2] = (v.z - m) * rs * gf.z + bf.z;
  lds[widx][lane * 4 + 3] = (v.w - m) * rs * gf.w + bf.w;
  __syncthreads();
  int vo = lane & 31, half = lane >> 5;
  const float* lp = &lds[widx][half * 128];
  const float* wp = wout + half * 128 * NVOCAB + vo;
  float acc = 0;
  #pragma unroll 4
  for (int d = 0; d < 128; ++d) acc += lp[d] * wp[d * NVOCAB];
  acc += __shfl_down(acc, 32, 64);
  if (lane < 32) out[bt * NVOCAB + vo] = acc + bout[vo];
}

extern "C" void kernel_launch(void* const* d_in, const int* in_sizes, int n_in,
                              void* d_out, int out_size, void* d_ws, size_t ws_size,
                              hipStream_t stream) {
  const int*   tokens = (const int*)d_in[0];
  const float* emb   = (const float*)d_in[1];
  const float* ffs   = (const float*)d_in[2];
  const float* ffb   = (const float*)d_in[3];
  const float* w1    = (const float*)d_in[4];
  const float* b1    = (const float*)d_in[5];
  const float* w2    = (const float*)d_in[6];
  const float* b2    = (const float*)d_in[7];
  const float* lnfs  = (const float*)d_in[8];
  const float* lnfb  = (const float*)d_in[9];
  const float* wout  = (const float*)d_in[10];
  const float* bout  = (const float*)d_in[11];
  float* out = (float*)d_out;

  char* ws = (char*)d_ws;
  float* x    = (float*)(ws);                         // 16 MB fp32
  float* y    = (float*)(ws + (size_t)16*1024*1024);  // 16 MB fp32
  u16*   buf8 = (u16*)  (ws + (size_t)32*1024*1024);  //  8 MB bf16 (xv then lnx)
  u16*   qk   = (u16*)  (ws + (size_t)40*1024*1024);  //  8 MB bf16 (qk, then W planes)
  u16*   h    = (u16*)  (ws + (size_t)48*1024*1024);  // 32 MB bf16
  float* ct   = (float*)(ws + (size_t)80*1024*1024);  //  4 MB
  float* st   = (float*)(ws + (size_t)84*1024*1024);  //  4 MB  (end: 88 MB)

  const size_t PLN = (size_t)DD * HDIM;               // 262144 elements / plane

  k_tables<<<4096, 256, 0, stream>>>(ct, st);
  k_embed<<<4096, 256, 0, stream>>>(tokens, emb, x);
  for (int L = 0; L < NLAYER; ++L){
    k_rope<<<2048, 256, 0, stream>>>(x, ct, st, qk, buf8);
    k_attn2<<<128, 512, 0, stream>>>(qk, buf8, x, y);
    k_ln  <<<4096, 256, 0, stream>>>(y, ffs + L*DD, ffb + L*DD, buf8);
    // qk region is dead now: reuse for the layer's hi/lo weight planes
    k_split<DD, HDIM><<<128, 256, 0, stream>>>(w1 + (size_t)L*DD*HDIM, qk,         qk + PLN);
    k_split<HDIM, DD><<<128, 256, 0, stream>>>(w2 + (size_t)L*HDIM*DD, qk + 2*PLN, qk + 3*PLN);
    k_gemm<DD, HDIM, 0><<<dim3(8, 128), 256, 0, stream>>>(
        buf8, qk, qk + PLN, b1 + L*HDIM, nullptr, nullptr, h);
    k_gemm<HDIM, DD, 1><<<dim3(2, 128), 256, 0, stream>>>(
        h, qk + 2*PLN, qk + 3*PLN, b2 + L*DD, y, x, nullptr);
  }
  k_final<<<4096, 256, 0, stream>>>(x, lnfs, lnfb, wout, bout, out);
}

// Round 6
// 804.909 us; speedup vs baseline: 6.7920x; 1.1132x over previous
//
#include <hip/hip_runtime.h>
#include <hip/hip_bf16.h>
#include <math.h>

#define BATCH 2
#define SEQL 8192
#define DD 256
#define HDIM 1024
#define NLAYER 6
#define WSZ 512
#define NVOCAB 32
#define PLN (DD*HDIM)   // 262144 elems per weight plane

typedef unsigned short u16;
typedef __attribute__((ext_vector_type(8))) short bf16x8;
typedef __attribute__((ext_vector_type(4))) float f32x4;

union B8 { uint4 u; bf16x8 b; ushort s[8]; uint w[4]; };

__device__ inline float bf2f(u16 v){
  unsigned int u = ((unsigned int)v) << 16;
  return __uint_as_float(u);
}
__device__ inline u16 f2bf(float f){
  unsigned int u = __float_as_uint(f);
  u += 0x7fff + ((u >> 16) & 1);   // RNE
  return (u16)(u >> 16);
}
__device__ inline float4 bf4_to_f4(ushort4 v){
  return make_float4(bf2f(v.x), bf2f(v.y), bf2f(v.z), bf2f(v.w));
}

// ---------------- one-time rope tables (fp64 internally) ----------------
__global__ void k_tables(float* __restrict__ ct, float* __restrict__ st){
  int idx = blockIdx.x * 256 + threadIdx.x;     // t*128 + i
  if (idx >= SEQL * 128) return;
  int t = idx >> 7, i = idx & 127;
  double freq = exp(-((double)(2 * i) / (double)DD) * log(10000.0));
  double fr = (double)t * freq;
  ct[idx] = (float)cos(fr);
  st[idx] = (float)sin(fr);
}

// ---------------- embedding gather (fp32 table) ----------------
__global__ void k_embed(const int* __restrict__ tokens, const float* __restrict__ emb,
                        float* __restrict__ x){
  int idx = blockIdx.x * 256 + threadIdx.x;     // bt*64 + dvec
  int bt = idx >> 6, dv = (idx & 63) << 2;
  int tok = tokens[bt];
  *(float4*)(x + bt * DD + dv) = *(const float4*)(emb + tok * DD + dv);
}

// ------- rope: x(fp32) -> qk (roped bf16) and xv (plain bf16 copy) -------
__global__ void k_rope(const float* __restrict__ x, const float* __restrict__ ct,
                       const float* __restrict__ st, u16* __restrict__ qk,
                       u16* __restrict__ xv){
  int idx = blockIdx.x * 256 + threadIdx.x;     // bt*32 + ivec  (half-dim /4)
  int bt = idx >> 5, iv = (idx & 31) << 2;
  int t = bt & (SEQL - 1);
  const float* xr = x + bt * DD;
  float4 x1 = *(const float4*)(xr + iv);
  float4 x2 = *(const float4*)(xr + 128 + iv);
  float4 c = *(const float4*)(ct + t * 128 + iv);
  float4 s = *(const float4*)(st + t * 128 + iv);
  ushort4 q1, q2, v1, v2;
  q1.x = f2bf(x1.x * c.x - x2.x * s.x);  q2.x = f2bf(x2.x * c.x + x1.x * s.x);
  q1.y = f2bf(x1.y * c.y - x2.y * s.y);  q2.y = f2bf(x2.y * c.y + x1.y * s.y);
  q1.z = f2bf(x1.z * c.z - x2.z * s.z);  q2.z = f2bf(x2.z * c.z + x1.z * s.z);
  q1.w = f2bf(x1.w * c.w - x2.w * s.w);  q2.w = f2bf(x2.w * c.w + x1.w * s.w);
  v1.x = f2bf(x1.x); v1.y = f2bf(x1.y); v1.z = f2bf(x1.z); v1.w = f2bf(x1.w);
  v2.x = f2bf(x2.x); v2.y = f2bf(x2.y); v2.z = f2bf(x2.z); v2.w = f2bf(x2.w);
  *(ushort4*)(qk + bt * DD + iv)       = q1;
  *(ushort4*)(qk + bt * DD + 128 + iv) = q2;
  *(ushort4*)(xv + bt * DD + iv)       = v1;
  *(ushort4*)(xv + bt * DD + 128 + iv) = v2;
}

// ---------------- MFMA sliding-window attention ----------------
// 256 blocks x 512 threads. Block: 64 queries. Wave (qh 0..3, kh 0..1):
// 16 queries x 32-key half of each 64-key tile. Prefetch pipeline:
// global loads for tile i+1 issue before compute(i).
__global__ void __launch_bounds__(512, 2) k_attn2(const u16* __restrict__ qk,
                                                  const u16* __restrict__ xv,
                                                  const float* __restrict__ x,
                                                  float* __restrict__ y){
  __shared__ char smem[65536];
  u16* Klds = (u16*)smem;               // 32 KB frag-major K tile
  u16* Vlds = (u16*)(smem + 32768);     // 32 KB frag-major V^T tile
  float* redbuf = (float*)smem;         // reused after main loop

  const int tid = threadIdx.x;
  const int lane = tid & 63;
  const int w = tid >> 6;
  const int qh = w >> 1, kh = w & 1;    // qh 0..3
  const int l15 = lane & 15, lg = lane >> 4;

  const int qb = blockIdx.x * 64;
  const int t0 = qb & (SEQL - 1);
  const size_t bbase = (size_t)(qb >> 13) << 13;

  // ---- preload Q B-frags (16 queries of this wave) ----
  uint4 qf[8];
  {
    const u16* qr = qk + (size_t)(qb + qh*16 + l15) * DD + lg*4;
    #pragma unroll
    for (int s = 0; s < 8; ++s){
      uint2 a = *(const uint2*)(qr + s*32);
      uint2 b = *(const uint2*)(qr + s*32 + 16);
      qf[s] = make_uint4(a.x, a.y, b.x, b.y);
    }
  }

  f32x4 oacc[16];
  #pragma unroll
  for (int d = 0; d < 16; ++d) oacc[d] = (f32x4){0.f, 0.f, 0.f, 0.f};
  float lacc = 0.f;

  const int p0 = (t0 >= WSZ) ? (t0 - WSZ) : 0;
  const int ntile = ((t0 - p0) >> 6) + 1;

  const int sk15 = tid & 15, skt = (tid >> 4) & 3, sc = tid >> 6;   // K stage
  const int sdh = tid & 31, sk0 = (tid >> 5) * 4;                   // V stage
  const int vkhw = sk0 >> 5, vh = (sk0 >> 4) & 1, vlgw = (sk0 >> 2) & 3;

  uint4 kreg[4];
  uint  vreg[4][4];

  // ---- load + write tile 0 ----
  {
    const u16* sb = qk + (bbase + (size_t)p0 + skt*16 + sk15) * DD;
    #pragma unroll
    for (int u = 0; u < 4; ++u) kreg[u] = *(const uint4*)(sb + u*64 + sc*8);
    #pragma unroll
    for (int u = 0; u < 4; ++u){
      int d0 = sdh*2 + u*64;
      const u16* vb = xv + (bbase + (size_t)p0 + sk0) * DD + d0;
      vreg[u][0] = *(const uint*)(vb);
      vreg[u][1] = *(const uint*)(vb + DD);
      vreg[u][2] = *(const uint*)(vb + 2*DD);
      vreg[u][3] = *(const uint*)(vb + 3*DD);
    }
  }
  #pragma unroll
  for (int u = 0; u < 4; ++u){
    int d0 = u*64 + sc*8;
    int s = d0 >> 5, r = d0 & 31;
    int h = r >> 4, lgw = (r & 15) >> 2;
    int rec = ((s*4 + skt)*4 + lgw)*16 + sk15;
    char* wp = (char*)Klds + rec*16 + h*8;
    *(uint2*)wp         = make_uint2(kreg[u].x, kreg[u].y);
    *(uint2*)(wp + 256) = make_uint2(kreg[u].z, kreg[u].w);
  }
  #pragma unroll
  for (int u = 0; u < 4; ++u){
    int d0 = sdh*2 + u*64;
    uint a0 = vreg[u][0], a1 = vreg[u][1], a2 = vreg[u][2], a3 = vreg[u][3];
    uint w0 = (a0 & 0xffffu) | (a1 << 16);
    uint w1 = (a2 & 0xffffu) | (a3 << 16);
    uint w2 = (a0 >> 16) | (a1 & 0xffff0000u);
    uint w3 = (a2 >> 16) | (a3 & 0xffff0000u);
    int dimt = d0 >> 4, d15 = d0 & 15;
    int rec = ((dimt*2 + vkhw)*4 + vlgw)*16 + d15;
    char* wp = (char*)Vlds + rec*16 + vh*8;
    *(uint2*)wp        = make_uint2(w0, w1);
    *(uint2*)(wp + 16) = make_uint2(w2, w3);
  }
  __syncthreads();

  for (int ti = 0; ti < ntile; ++ti){
    const int p = p0 + ti*64;
    // issue next tile's global loads (fly under compute)
    if (ti + 1 < ntile){
      const int pn = p + 64;
      const u16* sb = qk + (bbase + (size_t)pn + skt*16 + sk15) * DD;
      #pragma unroll
      for (int u = 0; u < 4; ++u) kreg[u] = *(const uint4*)(sb + u*64 + sc*8);
      #pragma unroll
      for (int u = 0; u < 4; ++u){
        int d0 = sdh*2 + u*64;
        const u16* vb = xv + (bbase + (size_t)pn + sk0) * DD + d0;
        vreg[u][0] = *(const uint*)(vb);
        vreg[u][1] = *(const uint*)(vb + DD);
        vreg[u][2] = *(const uint*)(vb + 2*DD);
        vreg[u][3] = *(const uint*)(vb + 3*DD);
      }
    }

    // --- S^T = K · Q^T (2 ktp x 8 d-steps) ---
    f32x4 sacc[2];
    sacc[0] = (f32x4){0.f,0.f,0.f,0.f};
    sacc[1] = (f32x4){0.f,0.f,0.f,0.f};
    #pragma unroll
    for (int s = 0; s < 8; ++s){
      B8 ka0, ka1, qbf;
      ka0.b = *(const bf16x8*)((char*)Klds + (((s*4 + kh*2+0)*4 + lg)*16 + l15)*16);
      ka1.b = *(const bf16x8*)((char*)Klds + (((s*4 + kh*2+1)*4 + lg)*16 + l15)*16);
      qbf.u = qf[s];
      sacc[0] = __builtin_amdgcn_mfma_f32_16x16x32_bf16(ka0.b, qbf.b, sacc[0], 0, 0, 0);
      sacc[1] = __builtin_amdgcn_mfma_f32_16x16x32_bf16(ka1.b, qbf.b, sacc[1], 0, 0, 0);
    }

    // --- mask + exp + pack P^T -> PV A-frag ---
    B8 pa;
    #pragma unroll
    for (int ktp = 0; ktp < 2; ++ktp){
      int kbase = p + kh*32 + ktp*16 + lg*4;
      int qpos = t0 + qh*16 + l15;
      #pragma unroll
      for (int r = 0; r < 4; ++r){
        int kpos = kbase + r;
        float sv = sacc[ktp][r] * 0.0625f;
        bool ok = (kpos <= qpos) && (qpos <= kpos + WSZ);
        float pv = ok ? __expf(sv) : 0.0f;
        lacc += pv;
        pa.s[ktp*4 + r] = f2bf(pv);
      }
    }

    // --- O += P · V ---
    #pragma unroll
    for (int dimt = 0; dimt < 16; ++dimt){
      B8 vb;
      vb.b = *(const bf16x8*)((char*)Vlds + (((dimt*2 + kh)*4 + lg)*16 + l15)*16);
      oacc[dimt] = __builtin_amdgcn_mfma_f32_16x16x32_bf16(pa.b, vb.b, oacc[dimt], 0, 0, 0);
    }

    __syncthreads();     // all waves done reading LDS
    if (ti + 1 < ntile){
      #pragma unroll
      for (int u = 0; u < 4; ++u){
        int d0 = u*64 + sc*8;
        int s = d0 >> 5, r = d0 & 31;
        int h = r >> 4, lgw = (r & 15) >> 2;
        int rec = ((s*4 + skt)*4 + lgw)*16 + sk15;
        char* wp = (char*)Klds + rec*16 + h*8;
        *(uint2*)wp         = make_uint2(kreg[u].x, kreg[u].y);
        *(uint2*)(wp + 256) = make_uint2(kreg[u].z, kreg[u].w);
      }
      #pragma unroll
      for (int u = 0; u < 4; ++u){
        int d0 = sdh*2 + u*64;
        uint a0 = vreg[u][0], a1 = vreg[u][1], a2 = vreg[u][2], a3 = vreg[u][3];
        uint w0 = (a0 & 0xffffu) | (a1 << 16);
        uint w1 = (a2 & 0xffffu) | (a3 << 16);
        uint w2 = (a0 >> 16) | (a1 & 0xffff0000u);
        uint w3 = (a2 >> 16) | (a3 & 0xffff0000u);
        int dimt = d0 >> 4, d15 = d0 & 15;
        int rec = ((dimt*2 + vkhw)*4 + vlgw)*16 + d15;
        char* wp = (char*)Vlds + rec*16 + vh*8;
        *(uint2*)wp        = make_uint2(w0, w1);
        *(uint2*)(wp + 16) = make_uint2(w2, w3);
      }
    }
    __syncthreads();     // LDS ready for next compute
  }

  // ---- combine kh halves + normalize + residual ----
  lacc += __shfl_xor(lacc, 16, 64);
  lacc += __shfl_xor(lacc, 32, 64);
  if (lane < 16) redbuf[kh*64 + qh*16 + l15] = lacc;
  __syncthreads();
  if (tid < 64) redbuf[128 + tid] = redbuf[tid] + redbuf[64 + tid];
  __syncthreads();

  float* opass = redbuf + 192;          // [2][64][36] fp32 per pass
  #pragma unroll
  for (int pass = 0; pass < 8; ++pass){
    #pragma unroll
    for (int dt = 0; dt < 2; ++dt){
      int dimt = pass*2 + dt;
      #pragma unroll
      for (int r = 0; r < 4; ++r){
        int qrow = qh*16 + lg*4 + r;
        opass[(kh*64 + qrow)*36 + dt*16 + l15] = oacc[dimt][r];
      }
    }
    __syncthreads();
    {
      int q = tid >> 3, dv = (tid & 7) * 4;
      float4 o0 = *(float4*)&opass[q*36 + dv];
      float4 o1 = *(float4*)&opass[(64 + q)*36 + dv];
      float inv = 1.0f / redbuf[128 + q];
      size_t gi = (size_t)(qb + q) * DD + pass*32 + dv;
      float4 xr = *(const float4*)(x + gi);
      float4 ov;
      ov.x = xr.x + (o0.x + o1.x) * inv;
      ov.y = xr.y + (o0.y + o1.y) * inv;
      ov.z = xr.z + (o0.z + o1.z) * inv;
      ov.w = xr.w + (o0.w + o1.w) * inv;
      *(float4*)(y + gi) = ov;
    }
    __syncthreads();
  }
}

// ---------------- layernorm (wave per token), fp32 in, bf16 out ----------------
__global__ void __launch_bounds__(256) k_ln(const float* __restrict__ in,
                                            const float* __restrict__ g,
                                            const float* __restrict__ b,
                                            u16* __restrict__ out){
  int wid = (blockIdx.x * 256 + threadIdx.x) >> 6;
  int lane = threadIdx.x & 63;
  float4 v = *(const float4*)(in + wid * DD + lane * 4);
  float s = v.x + v.y + v.z + v.w;
  float ss = v.x * v.x + v.y * v.y + v.z * v.z + v.w * v.w;
  #pragma unroll
  for (int o = 32; o; o >>= 1){ s += __shfl_xor(s, o, 64); ss += __shfl_xor(ss, o, 64); }
  float m = s * (1.0f / DD);
  float var = ss * (1.0f / DD) - m * m;
  float rs = rsqrtf(var + 1e-5f);
  float4 gf = *(const float4*)(g + lane * 4);
  float4 bf = *(const float4*)(b + lane * 4);
  ushort4 o4;
  o4.x = f2bf((v.x - m) * rs * gf.x + bf.x);
  o4.y = f2bf((v.y - m) * rs * gf.y + bf.y);
  o4.z = f2bf((v.z - m) * rs * gf.z + bf.z);
  o4.w = f2bf((v.w - m) * rs * gf.w + bf.w);
  *(ushort4*)(out + wid * DD + lane * 4) = o4;
}

// -------- weight split: fp32 W[K][N] -> frag-major hi/lo bf16 planes ----------
template<int KDIM, int NDIM>
__device__ __forceinline__ void split_one(const float* __restrict__ W,
                                          u16* __restrict__ Phi,
                                          u16* __restrict__ Plo, int idx){
  int c15 = idx & 15;
  int lg = (idx >> 4) & 3;
  int nt = (idx >> 6) % (NDIM/16);
  int ks = idx / ((NDIM/16) * 64);
  int col = nt*16 + c15;
  B8 hi, lo;
  #pragma unroll
  for (int j = 0; j < 8; ++j){
    int k = ks*32 + (j >> 2)*16 + lg*4 + (j & 3);
    float wv = W[(size_t)k * NDIM + col];
    u16 hv = f2bf(wv);
    hi.s[j] = hv;
    lo.s[j] = f2bf(wv - bf2f(hv));
  }
  *(uint4*)(Phi + (size_t)idx * 8) = hi.u;
  *(uint4*)(Plo + (size_t)idx * 8) = lo.u;
}

__global__ void __launch_bounds__(256) k_split2(const float* __restrict__ W1,
                                                const float* __restrict__ W2,
                                                u16* __restrict__ P){
  int b = blockIdx.x;
  if (b < 128) split_one<DD, HDIM>(W1, P, P + PLN, b*256 + threadIdx.x);
  else         split_one<HDIM, DD>(W2, P + 2*PLN, P + 3*PLN, (b - 128)*256 + threadIdx.x);
}

// ---------------- MFMA GEMM: C = A(bf16) @ (hi+lo planes) ----------------
// BM=BN=128, BK=64, 4 waves (2x2), 64x64/wave. EPI 0: bias+GELU -> bf16 h.
// EPI 1: bias + residual -> fp32 x.
template<int KDIM, int NDIM, int EPI>
__global__ void __launch_bounds__(256) k_gemm(const u16* __restrict__ A,
                                              const u16* __restrict__ BhG,
                                              const u16* __restrict__ BlG,
                                              const float* __restrict__ bias,
                                              const float* __restrict__ res,
                                              float* __restrict__ outf,
                                              u16* __restrict__ outh){
  __shared__ char smem[51200];
  char* As = smem;                            // [128][144B] padded row-major
  char* Bh = smem + 18432;                    // 16 KB frag-major hi
  char* Bl = smem + 34816;                    // 16 KB frag-major lo

  const int tid = threadIdx.x;
  const int lane = tid & 63;
  const int w = tid >> 6;
  const int wr = w >> 1, wc = w & 1;
  const int l15 = lane & 15, lg = lane >> 4;
  const int m0 = blockIdx.y * 128;
  const int n0 = blockIdx.x * 128;

  f32x4 acc[4][4];
  #pragma unroll
  for (int a = 0; a < 4; ++a)
    #pragma unroll
    for (int c = 0; c < 4; ++c)
      acc[a][c] = (f32x4){0.f,0.f,0.f,0.f};

  for (int kb = 0; kb < KDIM/64; ++kb){
    __syncthreads();
    #pragma unroll
    for (int p = 0; p < 4; ++p){
      int c = p*256 + tid;
      int row = c >> 3, cc = c & 7;
      uint4 v = *(const uint4*)(A + (size_t)(m0 + row) * KDIM + kb*64 + cc*8);
      *(uint4*)(As + row*144 + cc*16) = v;
    }
    #pragma unroll
    for (int s = 0; s < 2; ++s){
      size_t gbase = ((size_t)(kb*2 + s) * (NDIM/16) + (n0 >> 4)) * 64;  // recs
      const uint4* srcH = (const uint4*)BhG + gbase;
      const uint4* srcL = (const uint4*)BlG + gbase;
      #pragma unroll
      for (int rr = 0; rr < 2; ++rr){
        int r = rr*256 + tid;
        *(uint4*)(Bh + (s*512 + r)*16) = srcH[r];
        *(uint4*)(Bl + (s*512 + r)*16) = srcL[r];
      }
    }
    __syncthreads();

    #pragma unroll
    for (int s = 0; s < 2; ++s){
      B8 af[4], bhf[4], blf[4];
      #pragma unroll
      for (int a = 0; a < 4; ++a){
        const char* ab = As + (wr*64 + a*16 + l15)*144 + s*64 + lg*8;
        uint2 lo = *(const uint2*)ab;
        uint2 hi = *(const uint2*)(ab + 32);
        af[a].u = make_uint4(lo.x, lo.y, hi.x, hi.y);
      }
      #pragma unroll
      for (int c = 0; c < 4; ++c){
        int rec = s*512 + (wc*4 + c)*64 + lg*16 + l15;
        bhf[c].u = *(const uint4*)(Bh + rec*16);
        blf[c].u = *(const uint4*)(Bl + rec*16);
      }
      #pragma unroll
      for (int a = 0; a < 4; ++a)
        #pragma unroll
        for (int c = 0; c < 4; ++c){
          acc[a][c] = __builtin_amdgcn_mfma_f32_16x16x32_bf16(af[a].b, bhf[c].b, acc[a][c], 0, 0, 0);
          acc[a][c] = __builtin_amdgcn_mfma_f32_16x16x32_bf16(af[a].b, blf[c].b, acc[a][c], 0, 0, 0);
        }
    }
  }

  float bv[4];
  #pragma unroll
  for (int c = 0; c < 4; ++c) bv[c] = bias[n0 + wc*64 + c*16 + l15];

  #pragma unroll
  for (int a = 0; a < 4; ++a){
    #pragma unroll
    for (int c = 0; c < 4; ++c){
      #pragma unroll
      for (int r = 0; r < 4; ++r){
        int row = m0 + wr*64 + a*16 + lg*4 + r;
        int col = n0 + wc*64 + c*16 + l15;
        float v = acc[a][c][r] + bv[c];
        if (EPI == 0){
          float gl = 0.5f * v * (1.0f + erff(v * 0.70710678f));
          outh[(size_t)row * NDIM + col] = f2bf(gl);
        } else {
          outf[(size_t)row * NDIM + col] = v + res[(size_t)row * NDIM + col];
        }
      }
    }
  }
}

// ---------------- final LN + (256x32) projection, fp32 out ----------------
__global__ void __launch_bounds__(256) k_final(const float* __restrict__ x,
                                               const float* __restrict__ g,
                                               const float* __restrict__ b,
                                               const float* __restrict__ wout,
                                               const float* __restrict__ bout,
                                               float* __restrict__ out){
  __shared__ float lds[4][256];
  int widx = threadIdx.x >> 6, lane = threadIdx.x & 63;
  int bt = blockIdx.x * 4 + widx;
  float4 v = *(const float4*)(x + bt * DD + lane * 4);
  float s = v.x + v.y + v.z + v.w;
  float ss = v.x * v.x + v.y * v.y + v.z * v.z + v.w * v.w;
  #pragma unroll
  for (int o = 32; o; o >>= 1){ s += __shfl_xor(s, o, 64); ss += __shfl_xor(ss, o, 64); }
  float m = s * (1.0f / DD);
  float var = ss * (1.0f / DD) - m * m;
  float rs = rsqrtf(var + 1e-5f);
  float4 gf = *(const float4*)(g + lane * 4);
  float4 bf = *(const float4*)(b + lane * 4);
  lds[widx][lane * 4 + 0] = (v.x - m) * rs * gf.x + bf.x;
  lds[widx][lane * 4 + 1] = (v.y - m) * rs * gf.y + bf.y;
  lds[widx][lane * 4 + 2] = (v.z - m) * rs * gf.z + bf.z;
  lds[widx][lane * 4 + 3] = (v.w - m) * rs * gf.w + bf.w;
  __syncthreads();
  int vo = lane & 31, half = lane >> 5;
  const float* lp = &lds[widx][half * 128];
  const float* wp = wout + half * 128 * NVOCAB + vo;
  float acc = 0;
  #pragma unroll 4
  for (int d = 0; d < 128; ++d) acc += lp[d] * wp[d * NVOCAB];
  acc += __shfl_down(acc, 32, 64);
  if (lane < 32) out[bt * NVOCAB + vo] = acc + bout[vo];
}

extern "C" void kernel_launch(void* const* d_in, const int* in_sizes, int n_in,
                              void* d_out, int out_size, void* d_ws, size_t ws_size,
                              hipStream_t stream) {
  const int*   tokens = (const int*)d_in[0];
  const float* emb   = (const float*)d_in[1];
  const float* ffs   = (const float*)d_in[2];
  const float* ffb   = (const float*)d_in[3];
  const float* w1    = (const float*)d_in[4];
  const float* b1    = (const float*)d_in[5];
  const float* w2    = (const float*)d_in[6];
  const float* b2    = (const float*)d_in[7];
  const float* lnfs  = (const float*)d_in[8];
  const float* lnfb  = (const float*)d_in[9];
  const float* wout  = (const float*)d_in[10];
  const float* bout  = (const float*)d_in[11];
  float* out = (float*)d_out;

  char* ws = (char*)d_ws;
  float* x    = (float*)(ws);                         // 16 MB fp32
  float* y    = (float*)(ws + (size_t)16*1024*1024);  // 16 MB fp32
  u16*   buf8 = (u16*)  (ws + (size_t)32*1024*1024);  //  8 MB bf16 (xv then lnx)
  u16*   qk   = (u16*)  (ws + (size_t)40*1024*1024);  //  8 MB bf16 (qk, then W planes)
  u16*   h    = (u16*)  (ws + (size_t)48*1024*1024);  // 32 MB bf16
  float* ct   = (float*)(ws + (size_t)80*1024*1024);  //  4 MB
  float* st   = (float*)(ws + (size_t)84*1024*1024);  //  4 MB  (end: 88 MB)

  k_tables<<<4096, 256, 0, stream>>>(ct, st);
  k_embed<<<4096, 256, 0, stream>>>(tokens, emb, x);
  for (int L = 0; L < NLAYER; ++L){
    k_rope<<<2048, 256, 0, stream>>>(x, ct, st, qk, buf8);
    k_attn2<<<256, 512, 0, stream>>>(qk, buf8, x, y);
    k_ln  <<<4096, 256, 0, stream>>>(y, ffs + L*DD, ffb + L*DD, buf8);
    // qk region is dead now: reuse for the layer's hi/lo weight planes
    k_split2<<<256, 256, 0, stream>>>(w1 + (size_t)L*PLN, w2 + (size_t)L*PLN, qk);
    k_gemm<DD, HDIM, 0><<<dim3(8, 128), 256, 0, stream>>>(
        buf8, qk, qk + PLN, b1 + L*HDIM, nullptr, nullptr, h);
    k_gemm<HDIM, DD, 1><<<dim3(2, 128), 256, 0, stream>>>(
        h, qk + 2*PLN, qk + 3*PLN, b2 + L*DD, y, x, nullptr);
  }
  k_final<<<4096, 256, 0, stream>>>(x, lnfs, lnfb, wout, bout, out);
}